// Round 1
// baseline (717.794 us; speedup 1.0000x reference)
//
#include <hip/hip_runtime.h>

typedef __attribute__((ext_vector_type(8))) short short8;
typedef __attribute__((ext_vector_type(4))) float float4v;

#define SDIM 64

// output tensor offsets (floats)
#define MU_OFF   0
#define COV_OFF  1536000
#define OP_OFF   4608000
#define SH_OFF   5120000

__device__ __forceinline__ float bf2f(unsigned short u){ return __uint_as_float(((unsigned)u)<<16); }
__device__ __forceinline__ unsigned short f2bf(float f){
  unsigned u = __float_as_uint(f);
  return (unsigned short)((u + 0x7fffu + ((u>>16)&1u)) >> 16);
}

// ---------------- prep: bf16 conversions + pt_part ----------------
// seg0: w1b [1024*256]   = bf16(se_w1)
// seg1: w2t [256n][256k] = bf16(gep_w2[k][n])
// seg2: w3p [32j][256k]  = bf16(j<19 ? gep_w3[k][j] : 0)
// seg3: ptb [1000p][256k]= bf16(sum_d cpts[p][d]*gep_w1[64+d][k])
__global__ __launch_bounds__(256) void kprep(
    const float* __restrict__ se_w1, const float* __restrict__ gep_w2,
    const float* __restrict__ gep_w3, const float* __restrict__ gep_w1,
    const float* __restrict__ cpts,
    unsigned short* __restrict__ w1b, unsigned short* __restrict__ w2t,
    unsigned short* __restrict__ w3p, unsigned short* __restrict__ ptb){
  int idx = blockIdx.x*256 + threadIdx.x;
  if (idx < 262144){ w1b[idx] = f2bf(se_w1[idx]); return; }
  int i1 = idx - 262144;
  if (i1 < 65536){ int n = i1 >> 8, k = i1 & 255; w2t[i1] = f2bf(gep_w2[k*256+n]); return; }
  int i2 = idx - 327680;
  if (i2 < 8192){ int j = i2 >> 8, k = i2 & 255; w3p[i2] = f2bf(j < 19 ? gep_w3[k*19+j] : 0.f); return; }
  int i3 = idx - 335872;
  if (i3 < 256000){ int p = i3 >> 8, k = i3 & 255;
    float v = cpts[p*3+0]*gep_w1[(SDIM+0)*256+k]
            + cpts[p*3+1]*gep_w1[(SDIM+1)*256+k]
            + cpts[p*3+2]*gep_w1[(SDIM+2)*256+k];
    ptb[i3] = f2bf(v);
  }
}

// ---------------- entity MLP: h=LN(relu? no: LN then relu), style, ent_part ----------------
__global__ __launch_bounds__(256) void kent(
    const float* __restrict__ ef, const int* __restrict__ cls_lab,
    const unsigned short* __restrict__ w1b, const float* __restrict__ se_b1,
    const float* __restrict__ se_gamma, const float* __restrict__ se_beta,
    const float* __restrict__ se_w2, const float* __restrict__ se_b2,
    const float* __restrict__ gep_w1, const float* __restrict__ gep_b1,
    float* __restrict__ entp){
  __shared__ float efL[1024];
  __shared__ float hrL[256];
  __shared__ float redL[16];
  __shared__ float styR[4][64];
  __shared__ float styL[64];
  int e = blockIdx.x, t = threadIdx.x;
  ((float4v*)efL)[t] = ((const float4v*)(ef + e*1024))[t];
  __syncthreads();
  float a0=0.f,a1=0.f,a2=0.f,a3=0.f;
  #pragma unroll 4
  for (int k=0;k<1024;k+=4){
    a0 += efL[k]   * bf2f(w1b[(k  )*256+t]);
    a1 += efL[k+1] * bf2f(w1b[(k+1)*256+t]);
    a2 += efL[k+2] * bf2f(w1b[(k+2)*256+t]);
    a3 += efL[k+3] * bf2f(w1b[(k+3)*256+t]);
  }
  float h = (a0+a1)+(a2+a3) + se_b1[t];
  // block reduce sum, sumsq over 256
  float s1 = h, s2 = h*h;
  #pragma unroll
  for (int o=32;o>0;o>>=1){ s1 += __shfl_xor(s1,o,64); s2 += __shfl_xor(s2,o,64); }
  int wid = t>>6, lane = t&63;
  if (lane==0){ redL[wid]=s1; redL[8+wid]=s2; }
  __syncthreads();
  float S1 = redL[0]+redL[1]+redL[2]+redL[3];
  float S2 = redL[8]+redL[9]+redL[10]+redL[11];
  float mean = S1*(1.f/256.f);
  float var  = S2*(1.f/256.f) - mean*mean;
  float hn = (h-mean)*rsqrtf(var+1e-5f)*se_gamma[t] + se_beta[t];
  hrL[t] = fmaxf(hn, 0.f);
  __syncthreads();
  // style = relu(LN) @ se_w2 + b2   (256->64), split K over 4 thread-quarters
  int s = t & 63, q = t >> 6;
  float st = 0.f;
  #pragma unroll 4
  for (int k=q*64;k<q*64+64;k++) st += hrL[k]*se_w2[k*64+s];
  styR[q][s] = st;
  __syncthreads();
  if (t < 64) styL[t] = styR[0][t]+styR[1][t]+styR[2][t]+styR[3][t] + se_b2[t];
  __syncthreads();
  int c = cls_lab[e];
  float ep = gep_b1[t] + gep_w1[(SDIM+3+c)*256 + t];   // one-hot class row
  #pragma unroll 8
  for (int k=0;k<64;k++) ep += styL[k]*gep_w1[k*256+t];
  entp[e*256+t] = ep;
}

// ---------------- main: per-entity fused point MLP via MFMA ----------------
__global__ __launch_bounds__(256, 2) void kmain(
    const float* __restrict__ entp, const unsigned short* __restrict__ ptb,
    const unsigned short* __restrict__ w2t, const unsigned short* __restrict__ w3p,
    const float* __restrict__ gep_b2, const float* __restrict__ gep_b3,
    const int* __restrict__ adapter_ids,
    const float* __restrict__ mu_tab, const float* __restrict__ cov_tab,
    const float* __restrict__ op_tab, const float* __restrict__ sh_tab,
    float* __restrict__ out){
  __shared__ unsigned short h1L[64*256];   // 32KB, XOR-swizzled rows of 512B
  __shared__ unsigned short w3L[32*256];   // 16KB, same swizzle
  __shared__ float entL[256];
  __shared__ float b2L[256];
  __shared__ float b3L[32];
  int e = blockIdx.x, t = threadIdx.x;
  int lane = t & 63, wid = t >> 6;
  int l16 = lane & 15, kq = lane >> 4;

  entL[t] = entp[e*256+t];
  b2L[t]  = gep_b2[t];
  if (t < 32) b3L[t] = (t < 19) ? gep_b3[t] : 0.f;
  // stage W3 padded [32][256] bf16 into LDS, swizzled (1024 16B granules / 4 per thread)
  #pragma unroll
  for (int i=0;i<4;i++){
    int g = t + i*256; int row = g>>5; int kg = g&31;
    uint4 v = *(const uint4*)(w3p + row*256 + kg*8);
    int bo = (row*512 + kg*16) ^ ((row&7)<<4);
    *(uint4*)((char*)w3L + bo) = v;
  }
  // persistent B fragments: this wave's 64-col slice of W2, all K (32 frags x 4 VGPR = 128 VGPR)
  short8 bB[8][4];
  #pragma unroll
  for (int s=0;s<8;s++)
    #pragma unroll
    for (int r=0;r<4;r++){
      int n  = wid*64 + r*16 + l16;
      int k0 = s*32 + kq*8;
      bB[s][r] = *(const short8*)(w2t + n*256 + k0);
    }
  __syncthreads();
  // each thread's 8 ent values (its k-granule is fixed: kg == t&31 for all i)
  float er[8];
  int kg0 = (t & 31)*8;
  #pragma unroll
  for (int j=0;j<8;j++) er[j] = entL[kg0+j];

  int aid = adapter_ids[e];
  const float* muT  = mu_tab  + aid*3000;
  const float* covT = cov_tab + aid*6000;
  const float* opT  = op_tab  + aid*1000;
  const float* shT  = sh_tab  + aid*9000;

  for (int c=0;c<16;c++){
    int p0 = c*64;
    // ---- build h1 = relu(ent + pt) in bf16, swizzled ----
    #pragma unroll
    for (int i=0;i<8;i++){
      int g = t + i*256; int row = g>>5; int kg = g&31;
      int p = p0 + row; p = (p>999)?999:p;       // clamp; garbage rows masked at write
      uint4 pv = *(const uint4*)(ptb + p*256 + kg*8);
      unsigned pw[4] = {pv.x, pv.y, pv.z, pv.w};
      unsigned rw[4];
      #pragma unroll
      for (int w=0; w<4; w++){
        float f0 = bf2f((unsigned short)(pw[w] & 0xffffu)) + er[2*w];
        float f1 = bf2f((unsigned short)(pw[w] >> 16))     + er[2*w+1];
        f0 = fmaxf(f0, 0.f); f1 = fmaxf(f1, 0.f);
        rw[w] = (unsigned)f2bf(f0) | ((unsigned)f2bf(f1) << 16);
      }
      int bo = (row*512 + kg*16) ^ ((row&7)<<4);
      *(uint4*)((char*)h1L + bo) = make_uint4(rw[0],rw[1],rw[2],rw[3]);
    }
    __syncthreads();
    // ---- GEMM1: h2 = relu(h1 @ W2 + b2), wave tile 64pts x 64cols ----
    float4v acc[4][4];
    #pragma unroll
    for (int m=0;m<4;m++)
      #pragma unroll
      for (int r=0;r<4;r++) acc[m][r] = (float4v){0.f,0.f,0.f,0.f};
    #pragma unroll
    for (int s=0;s<8;s++){
      short8 a[4];
      #pragma unroll
      for (int m=0;m<4;m++){
        int row = m*16 + l16;
        int bo = (row*512 + s*64 + kq*16) ^ ((row&7)<<4);
        a[m] = *(const short8*)((char*)h1L + bo);
      }
      #pragma unroll
      for (int m=0;m<4;m++)
        #pragma unroll
        for (int r=0;r<4;r++)
          acc[m][r] = __builtin_amdgcn_mfma_f32_16x16x32_bf16(a[m], bB[s][r], acc[m][r], 0,0,0);
    }
    __syncthreads();
    // ---- h2 -> h1L (reuse), relu+bias, bf16, swizzled ----
    #pragma unroll
    for (int m=0;m<4;m++)
      #pragma unroll
      for (int r=0;r<4;r++){
        int n = wid*64 + r*16 + l16;
        float bias = b2L[n];
        #pragma unroll
        for (int j=0;j<4;j++){
          int row = m*16 + kq*4 + j;
          float v = fmaxf(acc[m][r][j] + bias, 0.f);
          int bo = (row*512 + n*2) ^ ((row&7)<<4);
          *(unsigned short*)((char*)h1L + bo) = f2bf(v);
        }
      }
    __syncthreads();
    // ---- GEMM2: params = h2 @ W3pad, wave handles 16 rows ----
    float4v acc2[2];
    acc2[0] = (float4v){0.f,0.f,0.f,0.f};
    acc2[1] = (float4v){0.f,0.f,0.f,0.f};
    #pragma unroll
    for (int s=0;s<8;s++){
      int arow = wid*16 + l16;
      int abo = (arow*512 + s*64 + kq*16) ^ ((arow&7)<<4);
      short8 a2 = *(const short8*)((char*)h1L + abo);
      #pragma unroll
      for (int r=0;r<2;r++){
        int brow = r*16 + l16;
        int bbo = (brow*512 + s*64 + kq*16) ^ ((brow&7)<<4);
        short8 bw = *(const short8*)((char*)w3L + bbo);
        acc2[r] = __builtin_amdgcn_mfma_f32_16x16x32_bf16(a2, bw, acc2[r], 0,0,0);
      }
    }
    // ---- epilogue: bias, sigmoid(col9), + adapter tables, scatter to 4 outputs ----
    #pragma unroll
    for (int r=0;r<2;r++)
      #pragma unroll
      for (int j=0;j<4;j++){
        int prow = wid*16 + kq*4 + j;
        int p = p0 + prow;
        int ncol = r*16 + l16;
        if (p < 1000 && ncol < 19){
          float v = acc2[r][j] + b3L[ncol];
          int pi = e*1000 + p;
          if (ncol < 3)       out[MU_OFF  + pi*3 + ncol]      = v + muT[p*3+ncol];
          else if (ncol < 9)  out[COV_OFF + pi*6 + (ncol-3)]  = v + covT[p*6 + ncol-3];
          else if (ncol == 9) out[OP_OFF  + pi]               = 1.f/(1.f+__expf(-v)) + opT[p];
          else                out[SH_OFF  + pi*9 + (ncol-10)] = v + shT[p*9 + ncol-10];
        }
      }
    __syncthreads();   // protect h1L before next chunk's writes
  }
}

extern "C" void kernel_launch(void* const* d_in, const int* in_sizes, int n_in,
                              void* d_out, int out_size, void* d_ws, size_t ws_size,
                              hipStream_t stream){
  const float* ef    = (const float*)d_in[0];
  const int*   cls   = (const int*)d_in[1];
  const int*   aid   = (const int*)d_in[2];
  const float* se_w1 = (const float*)d_in[3];
  const float* se_b1 = (const float*)d_in[4];
  const float* se_g  = (const float*)d_in[5];
  const float* se_be = (const float*)d_in[6];
  const float* se_w2 = (const float*)d_in[7];
  const float* se_b2 = (const float*)d_in[8];
  const float* cpts  = (const float*)d_in[9];
  const float* gw1   = (const float*)d_in[10];
  const float* gb1   = (const float*)d_in[11];
  const float* gw2   = (const float*)d_in[12];
  const float* gb2   = (const float*)d_in[13];
  const float* gw3   = (const float*)d_in[14];
  const float* gb3   = (const float*)d_in[15];
  const float* mu_t  = (const float*)d_in[16];
  const float* cov_t = (const float*)d_in[17];
  const float* op_t  = (const float*)d_in[18];
  const float* sh_t  = (const float*)d_in[19];
  float* out = (float*)d_out;
  char* ws = (char*)d_ws;
  unsigned short* w1b = (unsigned short*)(ws);                // 524288 B
  unsigned short* w2t = (unsigned short*)(ws + 524288);       // 131072 B
  unsigned short* w3p = (unsigned short*)(ws + 655360);       // 16384  B
  unsigned short* ptb = (unsigned short*)(ws + 671744);       // 512000 B
  float*          entp= (float*)(ws + 1183744);               // 524288 B  (total ~1.7MB)

  kprep<<<2312, 256, 0, stream>>>(se_w1, gw2, gw3, gw1, cpts, w1b, w2t, w3p, ptb);
  kent <<<512, 256, 0, stream>>>(ef, cls, w1b, se_b1, se_g, se_be, se_w2, se_b2, gw1, gb1, entp);
  kmain<<<512, 256, 0, stream>>>(entp, ptb, w2t, w3p, gb2, gb3, aid, mu_t, cov_t, op_t, sh_t, out);
}

// Round 2
// 183.775 us; speedup vs baseline: 3.9058x; 3.9058x over previous
//
#include <hip/hip_runtime.h>

typedef __attribute__((ext_vector_type(8))) short short8;
typedef __attribute__((ext_vector_type(4))) float float4v;

#define SDIM 64

// output tensor offsets (floats)
#define MU_OFF   0
#define COV_OFF  1536000
#define OP_OFF   4608000
#define SH_OFF   5120000

__device__ __forceinline__ float bf2f(unsigned short u){ return __uint_as_float(((unsigned)u)<<16); }
__device__ __forceinline__ unsigned short f2bf(float f){
  unsigned u = __float_as_uint(f);
  return (unsigned short)((u + 0x7fffu + ((u>>16)&1u)) >> 16);
}

// ---------------- prep: bf16 conversions + pt_part ----------------
// seg0: w1b [1024*256]   = bf16(se_w1)
// seg1: w2t [256n][256k] = bf16(gep_w2[k][n])
// seg2: w3p [32j][256k]  = bf16(j<19 ? gep_w3[k][j] : 0)
// seg3: ptb [1000p][256k]= bf16(sum_d cpts[p][d]*gep_w1[64+d][k])
__global__ __launch_bounds__(256) void kprep(
    const float* __restrict__ se_w1, const float* __restrict__ gep_w2,
    const float* __restrict__ gep_w3, const float* __restrict__ gep_w1,
    const float* __restrict__ cpts,
    unsigned short* __restrict__ w1b, unsigned short* __restrict__ w2t,
    unsigned short* __restrict__ w3p, unsigned short* __restrict__ ptb){
  int idx = blockIdx.x*256 + threadIdx.x;
  if (idx < 262144){ w1b[idx] = f2bf(se_w1[idx]); return; }
  int i1 = idx - 262144;
  if (i1 < 65536){ int n = i1 >> 8, k = i1 & 255; w2t[i1] = f2bf(gep_w2[k*256+n]); return; }
  int i2 = idx - 327680;
  if (i2 < 8192){ int j = i2 >> 8, k = i2 & 255; w3p[i2] = f2bf(j < 19 ? gep_w3[k*19+j] : 0.f); return; }
  int i3 = idx - 335872;
  if (i3 < 256000){ int p = i3 >> 8, k = i3 & 255;
    float v = cpts[p*3+0]*gep_w1[(SDIM+0)*256+k]
            + cpts[p*3+1]*gep_w1[(SDIM+1)*256+k]
            + cpts[p*3+2]*gep_w1[(SDIM+2)*256+k];
    ptb[i3] = f2bf(v);
  }
}

// ---------------- entity MLP: LN -> relu -> style -> ent_part ----------------
__global__ __launch_bounds__(256) void kent(
    const float* __restrict__ ef, const int* __restrict__ cls_lab,
    const unsigned short* __restrict__ w1b, const float* __restrict__ se_b1,
    const float* __restrict__ se_gamma, const float* __restrict__ se_beta,
    const float* __restrict__ se_w2, const float* __restrict__ se_b2,
    const float* __restrict__ gep_w1, const float* __restrict__ gep_b1,
    float* __restrict__ entp){
  __shared__ float efL[1024];
  __shared__ float hrL[256];
  __shared__ float redL[16];
  __shared__ float styR[4][64];
  __shared__ float styL[64];
  int e = blockIdx.x, t = threadIdx.x;
  ((float4v*)efL)[t] = ((const float4v*)(ef + e*1024))[t];
  __syncthreads();
  float a0=0.f,a1=0.f,a2=0.f,a3=0.f;
  #pragma unroll 4
  for (int k=0;k<1024;k+=4){
    a0 += efL[k]   * bf2f(w1b[(k  )*256+t]);
    a1 += efL[k+1] * bf2f(w1b[(k+1)*256+t]);
    a2 += efL[k+2] * bf2f(w1b[(k+2)*256+t]);
    a3 += efL[k+3] * bf2f(w1b[(k+3)*256+t]);
  }
  float h = (a0+a1)+(a2+a3) + se_b1[t];
  float s1 = h, s2 = h*h;
  #pragma unroll
  for (int o=32;o>0;o>>=1){ s1 += __shfl_xor(s1,o,64); s2 += __shfl_xor(s2,o,64); }
  int wid = t>>6, lane = t&63;
  if (lane==0){ redL[wid]=s1; redL[8+wid]=s2; }
  __syncthreads();
  float S1 = redL[0]+redL[1]+redL[2]+redL[3];
  float S2 = redL[8]+redL[9]+redL[10]+redL[11];
  float mean = S1*(1.f/256.f);
  float var  = S2*(1.f/256.f) - mean*mean;
  float hn = (h-mean)*rsqrtf(var+1e-5f)*se_gamma[t] + se_beta[t];
  hrL[t] = fmaxf(hn, 0.f);
  __syncthreads();
  int s = t & 63, q = t >> 6;
  float st = 0.f;
  #pragma unroll 4
  for (int k=q*64;k<q*64+64;k++) st += hrL[k]*se_w2[k*64+s];
  styR[q][s] = st;
  __syncthreads();
  if (t < 64) styL[t] = styR[0][t]+styR[1][t]+styR[2][t]+styR[3][t] + se_b2[t];
  __syncthreads();
  int c = cls_lab[e];
  float ep = gep_b1[t] + gep_w1[(SDIM+3+c)*256 + t];
  #pragma unroll 8
  for (int k=0;k<64;k++) ep += styL[k]*gep_w1[k*256+t];
  entp[e*256+t] = ep;
}

// ---------------- main: per-entity fused point MLP via MFMA ----------------
// 512 threads = 8 waves; each wave owns 32 output cols of GEMM1.
// Persistent B (W2 slice) = 16 short8 = 64 VGPR/thread. No spill.
__global__ __launch_bounds__(512, 2) void kmain(
    const float* __restrict__ entp, const unsigned short* __restrict__ ptb,
    const unsigned short* __restrict__ w2t, const unsigned short* __restrict__ w3p,
    const float* __restrict__ gep_b2, const float* __restrict__ gep_b3,
    const int* __restrict__ adapter_ids,
    const float* __restrict__ mu_tab, const float* __restrict__ cov_tab,
    const float* __restrict__ op_tab, const float* __restrict__ sh_tab,
    float* __restrict__ out){
  __shared__ unsigned short h1L[64*256];   // 32KB, XOR-swizzled rows of 512B
  __shared__ unsigned short w3L[32*256];   // 16KB, same swizzle
  __shared__ float entL[256];
  __shared__ float b2L[256];
  __shared__ float b3L[32];
  __shared__ float pL[64][20];             // param staging for coalesced epilogue
  int e = blockIdx.x, t = threadIdx.x;
  int lane = t & 63, wid = t >> 6;        // wid 0..7
  int l16 = lane & 15, kq = lane >> 4;

  if (t < 256){ entL[t] = entp[e*256+t]; b2L[t] = gep_b2[t]; }
  if (t < 32) b3L[t] = (t < 19) ? gep_b3[t] : 0.f;
  // stage W3 padded [32][256] bf16 into LDS, swizzled (1024 16B granules / 2 per thread)
  #pragma unroll
  for (int i=0;i<2;i++){
    int g = t + i*512; int row = g>>5; int kg = g&31;
    uint4 v = *(const uint4*)(w3p + row*256 + kg*8);
    int bo = (row*512 + kg*16) ^ ((row&7)<<4);
    *(uint4*)((char*)w3L + bo) = v;
  }
  // persistent B fragments: this wave's 32-col slice of W2, all K (16 frags = 64 VGPR)
  short8 bB[8][2];
  #pragma unroll
  for (int s=0;s<8;s++)
    #pragma unroll
    for (int r=0;r<2;r++){
      int n  = wid*32 + r*16 + l16;
      int k0 = s*32 + kq*8;
      bB[s][r] = *(const short8*)(w2t + n*256 + k0);
    }
  __syncthreads();
  // each thread's 8 ent values (its k-granule is fixed: kg == t&31 for all i)
  float er[8];
  int kg0 = (t & 31)*8;
  #pragma unroll
  for (int j=0;j<8;j++) er[j] = entL[kg0+j];

  int aid = adapter_ids[e];
  const float* muT  = mu_tab  + (size_t)aid*3000;
  const float* covT = cov_tab + (size_t)aid*6000;
  const float* opT  = op_tab  + (size_t)aid*1000;
  const float* shT  = sh_tab  + (size_t)aid*9000;

  for (int c=0;c<16;c++){
    int p0 = c*64;
    int valid = 1000 - p0; if (valid > 64) valid = 64;
    // ---- build h1 = relu(ent + pt) in bf16, swizzled (2048 granules / 4 per thread) ----
    #pragma unroll
    for (int i=0;i<4;i++){
      int g = t + i*512; int row = g>>5; int kg = g&31;
      int p = p0 + row; p = (p>999)?999:p;       // clamp; garbage rows masked at write
      uint4 pv = *(const uint4*)(ptb + p*256 + kg*8);
      unsigned pw[4] = {pv.x, pv.y, pv.z, pv.w};
      unsigned rw[4];
      #pragma unroll
      for (int w=0; w<4; w++){
        float f0 = bf2f((unsigned short)(pw[w] & 0xffffu)) + er[2*w];
        float f1 = bf2f((unsigned short)(pw[w] >> 16))     + er[2*w+1];
        f0 = fmaxf(f0, 0.f); f1 = fmaxf(f1, 0.f);
        rw[w] = (unsigned)f2bf(f0) | ((unsigned)f2bf(f1) << 16);
      }
      int bo = (row*512 + kg*16) ^ ((row&7)<<4);
      *(uint4*)((char*)h1L + bo) = make_uint4(rw[0],rw[1],rw[2],rw[3]);
    }
    __syncthreads();                         // A
    // ---- GEMM1: h2 = relu(h1 @ W2 + b2), wave tile 64pts x 32cols ----
    float4v acc[4][2];
    #pragma unroll
    for (int m=0;m<4;m++){
      acc[m][0] = (float4v){0.f,0.f,0.f,0.f};
      acc[m][1] = (float4v){0.f,0.f,0.f,0.f};
    }
    #pragma unroll
    for (int s=0;s<8;s++){
      short8 a[4];
      #pragma unroll
      for (int m=0;m<4;m++){
        int row = m*16 + l16;
        int bo = (row*512 + s*64 + kq*16) ^ ((row&7)<<4);
        a[m] = *(const short8*)((char*)h1L + bo);
      }
      #pragma unroll
      for (int m=0;m<4;m++){
        acc[m][0] = __builtin_amdgcn_mfma_f32_16x16x32_bf16(a[m], bB[s][0], acc[m][0], 0,0,0);
        acc[m][1] = __builtin_amdgcn_mfma_f32_16x16x32_bf16(a[m], bB[s][1], acc[m][1], 0,0,0);
      }
    }
    __syncthreads();                         // B
    // ---- h2 -> h1L (reuse), relu+bias, bf16, swizzled ----
    #pragma unroll
    for (int m=0;m<4;m++)
      #pragma unroll
      for (int r=0;r<2;r++){
        int n = wid*32 + r*16 + l16;
        float bias = b2L[n];
        #pragma unroll
        for (int j=0;j<4;j++){
          int row = m*16 + kq*4 + j;
          float v = fmaxf(acc[m][r][j] + bias, 0.f);
          int bo = (row*512 + n*2) ^ ((row&7)<<4);
          *(unsigned short*)((char*)h1L + bo) = f2bf(v);
        }
      }
    __syncthreads();                         // C
    // ---- GEMM2: params = h2 @ W3pad; 8 waves = 4 row-groups x 2 col-halves ----
    {
      int rg = wid & 3;       // row group: rows rg*16..rg*16+15
      int ch = wid >> 2;      // col half: cols ch*16..ch*16+15
      float4v acc2 = (float4v){0.f,0.f,0.f,0.f};
      #pragma unroll
      for (int s=0;s<8;s++){
        int arow = rg*16 + l16;
        int abo = (arow*512 + s*64 + kq*16) ^ ((arow&7)<<4);
        short8 a2 = *(const short8*)((char*)h1L + abo);
        int brow = ch*16 + l16;
        int bbo = (brow*512 + s*64 + kq*16) ^ ((brow&7)<<4);
        short8 bw = *(const short8*)((char*)w3L + bbo);
        acc2 = __builtin_amdgcn_mfma_f32_16x16x32_bf16(a2, bw, acc2, 0,0,0);
      }
      int ncol = ch*16 + l16;
      #pragma unroll
      for (int j=0;j<4;j++){
        int prow = rg*16 + kq*4 + j;
        if (ncol < 19) pL[prow][ncol] = acc2[j] + b3L[ncol];
      }
    }
    __syncthreads();                         // D
    // ---- coalesced epilogue: params + adapter tables -> 4 output tensors ----
    {
      int base = e*1000 + p0;
      if (t < valid*3){
        int p = t/3, cc = t - p*3;
        out[MU_OFF + base*3 + t] = pL[p][cc] + muT[p0*3 + t];
      }
      if (t < valid*6){
        int p = t/6, cc = t - p*6;
        out[COV_OFF + base*6 + t] = pL[p][3+cc] + covT[p0*6 + t];
      }
      if (t < valid){
        float v = pL[t][9];
        out[OP_OFF + base + t] = 1.f/(1.f+__expf(-v)) + opT[p0 + t];
      }
      for (int idx = t; idx < valid*9; idx += 512){
        int p = idx/9, cc = idx - p*9;
        out[SH_OFF + base*9 + idx] = pL[p][10+cc] + shT[p0*9 + idx];
      }
    }
    // next chunk's h1 staging (writes h1L) is safe: GEMM2 reads finished before D;
    // pL next written only after next C.
  }
}

extern "C" void kernel_launch(void* const* d_in, const int* in_sizes, int n_in,
                              void* d_out, int out_size, void* d_ws, size_t ws_size,
                              hipStream_t stream){
  const float* ef    = (const float*)d_in[0];
  const int*   cls   = (const int*)d_in[1];
  const int*   aid   = (const int*)d_in[2];
  const float* se_w1 = (const float*)d_in[3];
  const float* se_b1 = (const float*)d_in[4];
  const float* se_g  = (const float*)d_in[5];
  const float* se_be = (const float*)d_in[6];
  const float* se_w2 = (const float*)d_in[7];
  const float* se_b2 = (const float*)d_in[8];
  const float* cpts  = (const float*)d_in[9];
  const float* gw1   = (const float*)d_in[10];
  const float* gb1   = (const float*)d_in[11];
  const float* gw2   = (const float*)d_in[12];
  const float* gb2   = (const float*)d_in[13];
  const float* gw3   = (const float*)d_in[14];
  const float* gb3   = (const float*)d_in[15];
  const float* mu_t  = (const float*)d_in[16];
  const float* cov_t = (const float*)d_in[17];
  const float* op_t  = (const float*)d_in[18];
  const float* sh_t  = (const float*)d_in[19];
  float* out = (float*)d_out;
  char* ws = (char*)d_ws;
  unsigned short* w1b = (unsigned short*)(ws);                // 524288 B
  unsigned short* w2t = (unsigned short*)(ws + 524288);       // 131072 B
  unsigned short* w3p = (unsigned short*)(ws + 655360);       // 16384  B
  unsigned short* ptb = (unsigned short*)(ws + 671744);       // 512000 B
  float*          entp= (float*)(ws + 1183744);               // 524288 B  (total ~1.7MB)

  kprep<<<2312, 256, 0, stream>>>(se_w1, gw2, gw3, gw1, cpts, w1b, w2t, w3p, ptb);
  kent <<<512, 256, 0, stream>>>(ef, cls, w1b, se_b1, se_g, se_be, se_w2, se_b2, gw1, gb1, entp);
  kmain<<<512, 512, 0, stream>>>(entp, ptb, w2t, w3p, gb2, gb3, aid, mu_t, cov_t, op_t, sh_t, out);
}